// Round 1
// baseline (47.867 us; speedup 1.0000x reference)
//
#include <hip/hip_runtime.h>

#define NQ 8
#define NLAYERS 3

// Amplitude layout: index i (8 bits) = (lane << 2) | j
//   qubit 0 -> bit0 of j, qubit 1 -> bit1 of j, qubit q>=2 -> bit (q-2) of lane.
// Each lane holds 4 complex amplitudes: ar[4], ai[4].

__device__ __forceinline__ void ry_pair(float c, float s, float& a0, float& a1) {
    float n0 = c * a0 - s * a1;
    float n1 = s * a0 + c * a1;
    a0 = n0; a1 = n1;
}

__device__ __forceinline__ void apply_ry(int q, float c, float s,
                                         float ar[4], float ai[4], int lane) {
    if (q == 0) {
        ry_pair(c, s, ar[0], ar[1]); ry_pair(c, s, ai[0], ai[1]);
        ry_pair(c, s, ar[2], ar[3]); ry_pair(c, s, ai[2], ai[3]);
    } else if (q == 1) {
        ry_pair(c, s, ar[0], ar[2]); ry_pair(c, s, ai[0], ai[2]);
        ry_pair(c, s, ar[1], ar[3]); ry_pair(c, s, ai[1], ai[3]);
    } else {
        int mask = 1 << (q - 2);
        float sgn = (lane & mask) ? s : -s;
#pragma unroll
        for (int j = 0; j < 4; ++j) {
            float pr = __shfl_xor(ar[j], mask);
            float pq = __shfl_xor(ai[j], mask);
            ar[j] = c * ar[j] + sgn * pr;
            ai[j] = c * ai[j] + sgn * pq;
        }
    }
}

__device__ __forceinline__ void rz_amp(float cp, float ssp, float& r, float& i) {
    // multiply (r + i*i) by (cp + i*ssp)
    float nr = r * cp - i * ssp;
    float ni = i * cp + r * ssp;
    r = nr; i = ni;
}

__device__ __forceinline__ void apply_rz(int q, float cp, float sp,
                                         float ar[4], float ai[4], int lane) {
    if (q == 0) {
        rz_amp(cp, -sp, ar[0], ai[0]); rz_amp(cp,  sp, ar[1], ai[1]);
        rz_amp(cp, -sp, ar[2], ai[2]); rz_amp(cp,  sp, ar[3], ai[3]);
    } else if (q == 1) {
        rz_amp(cp, -sp, ar[0], ai[0]); rz_amp(cp, -sp, ar[1], ai[1]);
        rz_amp(cp,  sp, ar[2], ai[2]); rz_amp(cp,  sp, ar[3], ai[3]);
    } else {
        float ssp = (lane & (1 << (q - 2))) ? sp : -sp;
#pragma unroll
        for (int j = 0; j < 4; ++j) rz_amp(cp, ssp, ar[j], ai[j]);
    }
}

// CNOT(c, (c+1)%8)
__device__ __forceinline__ void apply_cnot(int c, float ar[4], float ai[4], int lane) {
    if (c == 0) {              // ctrl=local bit0 (j=1,3), tgt=local bit1: swap j1<->j3
        float t;
        t = ar[1]; ar[1] = ar[3]; ar[3] = t;
        t = ai[1]; ai[1] = ai[3]; ai[3] = t;
    } else if (c == 1) {       // ctrl=local bit1 (j=2,3), tgt=lane bit0
        ar[2] = __shfl_xor(ar[2], 1); ai[2] = __shfl_xor(ai[2], 1);
        ar[3] = __shfl_xor(ar[3], 1); ai[3] = __shfl_xor(ai[3], 1);
    } else if (c == 7) {       // ctrl=lane bit5, tgt=local bit0: swap (0,1),(2,3) if hi
        bool hi = (lane & 32) != 0;
        float t0 = ar[0]; ar[0] = hi ? ar[1] : ar[0]; ar[1] = hi ? t0 : ar[1];
        float u0 = ai[0]; ai[0] = hi ? ai[1] : ai[0]; ai[1] = hi ? u0 : ai[1];
        float t2 = ar[2]; ar[2] = hi ? ar[3] : ar[2]; ar[3] = hi ? t2 : ar[3];
        float u2 = ai[2]; ai[2] = hi ? ai[3] : ai[2]; ai[3] = hi ? u2 : ai[3];
    } else {                   // c in 2..6: ctrl=lane bit (c-2), tgt=lane bit (c-1)
        int cm = 1 << (c - 2);
        int tm = 1 << (c - 1);
        bool hi = (lane & cm) != 0;
#pragma unroll
        for (int j = 0; j < 4; ++j) {
            float pr = __shfl_xor(ar[j], tm);
            float pq = __shfl_xor(ai[j], tm);
            ar[j] = hi ? pr : ar[j];
            ai[j] = hi ? pq : ai[j];
        }
    }
}

__global__ __launch_bounds__(256) void qmlp_fused(
    const float* __restrict__ x,        // [B,8]
    const float* __restrict__ qw,       // [3,8,2]
    const float* __restrict__ W1,       // [8,64]
    const float* __restrict__ b1,       // [64]
    const float* __restrict__ W2,       // [64,256]
    const float* __restrict__ b2,       // [256]
    float* __restrict__ out,            // [B,256]
    int B)
{
    __shared__ float vcos[NLAYERS * NQ * 2];
    __shared__ float vsin[NLAYERS * NQ * 2];

    int tid = threadIdx.x;
    if (tid < NLAYERS * NQ * 2) {
        float half = 0.5f * qw[tid];
        vcos[tid] = __cosf(half);
        vsin[tid] = __sinf(half);
    }
    __syncthreads();

    int lane = tid & 63;
    int wid  = tid >> 6;
    int sample = blockIdx.x * 4 + wid;
    if (sample >= B) return;

    // ---- load x row, normalize, encoding angles ----
    const float4* x4 = (const float4*)(x + sample * 8);
    float4 xa = x4[0], xb = x4[1];
    float xs[8] = {xa.x, xa.y, xa.z, xa.w, xb.x, xb.y, xb.z, xb.w};
    float xmin = xs[0], xmax = xs[0];
#pragma unroll
    for (int q = 1; q < 8; ++q) {
        xmin = fminf(xmin, xs[q]);
        xmax = fmaxf(xmax, xs[q]);
    }
    float inv = 1.0f / (xmax - xmin + 1e-8f);

    // ---- init |0..0> ----
    float ar[4] = {0.f, 0.f, 0.f, 0.f};
    float ai[4] = {0.f, 0.f, 0.f, 0.f};
    if (lane == 0) ar[0] = 1.0f;

    // ---- encoding RY(xn * pi) ----
#pragma unroll
    for (int q = 0; q < 8; ++q) {
        float half = (xs[q] - xmin) * inv * 1.5707963267948966f; // xn * pi/2
        float c = __cosf(half);
        float s = __sinf(half);
        apply_ry(q, c, s, ar, ai, lane);
    }

    // ---- variational layers ----
#pragma unroll
    for (int l = 0; l < NLAYERS; ++l) {
#pragma unroll
        for (int q = 0; q < 8; ++q) {
            int i0 = l * 16 + q * 2;
            apply_ry(q, vcos[i0],     vsin[i0],     ar, ai, lane);
            apply_rz(q, vcos[i0 + 1], vsin[i0 + 1], ar, ai, lane);
        }
#pragma unroll
        for (int q = 0; q < 8; ++q) apply_cnot(q, ar, ai, lane);
    }

    // ---- measurement <Z_q> ----
    float p[4];
#pragma unroll
    for (int j = 0; j < 4; ++j) p[j] = ar[j] * ar[j] + ai[j] * ai[j];

    float z[8];
    z[0] = (p[0] - p[1]) + (p[2] - p[3]);   // qubit0 = bit0 of j
    z[1] = (p[0] + p[1]) - (p[2] + p[3]);   // qubit1 = bit1 of j
    float sall = (p[0] + p[1]) + (p[2] + p[3]);
#pragma unroll
    for (int q = 2; q < 8; ++q)
        z[q] = (lane & (1 << (q - 2))) ? -sall : sall;

#pragma unroll
    for (int m = 1; m < 64; m <<= 1) {
#pragma unroll
        for (int q = 0; q < 8; ++q) z[q] += __shfl_xor(z[q], m);
    }
    // all lanes now hold the full z[0..7]

    // ---- MLP: h = relu(z @ W1 + b1); out = h @ W2 + b2 ----
    float h = b1[lane];
#pragma unroll
    for (int q = 0; q < 8; ++q) h += z[q] * W1[q * 64 + lane];
    h = fmaxf(h, 0.0f);

    int col = lane * 4;
    float4 acc = *(const float4*)(b2 + col);
#pragma unroll 8
    for (int i = 0; i < 64; ++i) {
        float hv = __shfl(h, i);
        float4 w = *(const float4*)(W2 + i * 256 + col);
        acc.x += hv * w.x;
        acc.y += hv * w.y;
        acc.z += hv * w.z;
        acc.w += hv * w.w;
    }
    *(float4*)(out + sample * 256 + col) = acc;
}

extern "C" void kernel_launch(void* const* d_in, const int* in_sizes, int n_in,
                              void* d_out, int out_size, void* d_ws, size_t ws_size,
                              hipStream_t stream) {
    const float* x  = (const float*)d_in[0];
    const float* qw = (const float*)d_in[1];
    const float* W1 = (const float*)d_in[2];
    const float* b1 = (const float*)d_in[3];
    const float* W2 = (const float*)d_in[4];
    const float* b2 = (const float*)d_in[5];
    float* out = (float*)d_out;

    int B = in_sizes[0] / NQ;          // 8192
    int blocks = (B + 3) / 4;          // 4 samples (waves) per 256-thread block

    qmlp_fused<<<blocks, 256, 0, stream>>>(x, qw, W1, b1, W2, b2, out, B);
}

// Round 2
// 34.738 us; speedup vs baseline: 1.3779x; 1.3779x over previous
//
#include <hip/hip_runtime.h>

#define NQ 8
#define NLAYERS 3

typedef unsigned int uint2ev __attribute__((ext_vector_type(2)));

// ---- cross-lane xor exchange, off the DS pipe where possible ----
// masks 1,2 -> DPP quad_perm; 8 -> DPP row_ror:8; 16/32 -> permlane*_swap (VALU).
// mask 4 has no DPP/permlane form -> stays __shfl_xor (ds_swizzle/bpermute).
template<int MASK>
__device__ __forceinline__ float xorlane(float v, int lane) {
    if constexpr (MASK == 1) {
        return __int_as_float(__builtin_amdgcn_mov_dpp(__float_as_int(v), 0xB1, 0xF, 0xF, false)); // quad_perm [1,0,3,2]
    } else if constexpr (MASK == 2) {
        return __int_as_float(__builtin_amdgcn_mov_dpp(__float_as_int(v), 0x4E, 0xF, 0xF, false)); // quad_perm [2,3,0,1]
    } else if constexpr (MASK == 8) {
        return __int_as_float(__builtin_amdgcn_mov_dpp(__float_as_int(v), 0x128, 0xF, 0xF, false)); // row_ror:8 == xor 8
    }
#if __has_builtin(__builtin_amdgcn_permlane16_swap)
    else if constexpr (MASK == 16) {
        uint2ev r = __builtin_amdgcn_permlane16_swap(__float_as_uint(v), __float_as_uint(v), false, false);
        return __uint_as_float((lane & 16) ? r.x : r.y);
    }
#endif
#if __has_builtin(__builtin_amdgcn_permlane32_swap)
    else if constexpr (MASK == 32) {
        uint2ev r = __builtin_amdgcn_permlane32_swap(__float_as_uint(v), __float_as_uint(v), false, false);
        return __uint_as_float((lane & 32) ? r.x : r.y);
    }
#endif
    else {
        return __shfl_xor(v, MASK);
    }
}

__device__ __forceinline__ void ry_pair(float c, float s, float& a0, float& a1) {
    float n0 = c * a0 - s * a1;
    float n1 = s * a0 + c * a1;
    a0 = n0; a1 = n1;
}

template<int Q>
__device__ __forceinline__ void apply_ry_t(float c, float s, float ar[4], float ai[4], int lane) {
    if constexpr (Q == 0) {
        ry_pair(c, s, ar[0], ar[1]); ry_pair(c, s, ai[0], ai[1]);
        ry_pair(c, s, ar[2], ar[3]); ry_pair(c, s, ai[2], ai[3]);
    } else if constexpr (Q == 1) {
        ry_pair(c, s, ar[0], ar[2]); ry_pair(c, s, ai[0], ai[2]);
        ry_pair(c, s, ar[1], ar[3]); ry_pair(c, s, ai[1], ai[3]);
    } else {
        constexpr int mask = 1 << (Q - 2);
        float sgn = (lane & mask) ? s : -s;
#pragma unroll
        for (int j = 0; j < 4; ++j) {
            float pr = xorlane<mask>(ar[j], lane);
            float pq = xorlane<mask>(ai[j], lane);
            ar[j] = c * ar[j] + sgn * pr;
            ai[j] = c * ai[j] + sgn * pq;
        }
    }
}

__device__ __forceinline__ void rz_amp(float cp, float ssp, float& r, float& i) {
    float nr = r * cp - i * ssp;
    float ni = i * cp + r * ssp;
    r = nr; i = ni;
}

template<int Q>
__device__ __forceinline__ void apply_rz_t(float cp, float sp, float ar[4], float ai[4], int lane) {
    if constexpr (Q == 0) {
        rz_amp(cp, -sp, ar[0], ai[0]); rz_amp(cp,  sp, ar[1], ai[1]);
        rz_amp(cp, -sp, ar[2], ai[2]); rz_amp(cp,  sp, ar[3], ai[3]);
    } else if constexpr (Q == 1) {
        rz_amp(cp, -sp, ar[0], ai[0]); rz_amp(cp, -sp, ar[1], ai[1]);
        rz_amp(cp,  sp, ar[2], ai[2]); rz_amp(cp,  sp, ar[3], ai[3]);
    } else {
        float ssp = (lane & (1 << (Q - 2))) ? sp : -sp;
#pragma unroll
        for (int j = 0; j < 4; ++j) rz_amp(cp, ssp, ar[j], ai[j]);
    }
}

// CNOT(c, (c+1)%8)
template<int C>
__device__ __forceinline__ void apply_cnot_t(float ar[4], float ai[4], int lane) {
    if constexpr (C == 0) {              // ctrl local bit0, tgt local bit1: swap j1<->j3
        float t;
        t = ar[1]; ar[1] = ar[3]; ar[3] = t;
        t = ai[1]; ai[1] = ai[3]; ai[3] = t;
    } else if constexpr (C == 1) {       // ctrl local bit1 (j=2,3), tgt lane bit0
        ar[2] = xorlane<1>(ar[2], lane); ai[2] = xorlane<1>(ai[2], lane);
        ar[3] = xorlane<1>(ar[3], lane); ai[3] = xorlane<1>(ai[3], lane);
    } else if constexpr (C == 7) {       // ctrl lane bit5, tgt local bit0
        bool hi = (lane & 32) != 0;
        float t0 = ar[0]; ar[0] = hi ? ar[1] : ar[0]; ar[1] = hi ? t0 : ar[1];
        float u0 = ai[0]; ai[0] = hi ? ai[1] : ai[0]; ai[1] = hi ? u0 : ai[1];
        float t2 = ar[2]; ar[2] = hi ? ar[3] : ar[2]; ar[3] = hi ? t2 : ar[3];
        float u2 = ai[2]; ai[2] = hi ? ai[3] : ai[2]; ai[3] = hi ? u2 : ai[3];
    } else {                             // c in 2..6: ctrl lane bit (c-2), tgt lane bit (c-1)
        constexpr int cm = 1 << (C - 2);
        constexpr int tm = 1 << (C - 1);
        bool hi = (lane & cm) != 0;
#pragma unroll
        for (int j = 0; j < 4; ++j) {
            float pr = xorlane<tm>(ar[j], lane);
            float pq = xorlane<tm>(ai[j], lane);
            ar[j] = hi ? pr : ar[j];
            ai[j] = hi ? pq : ai[j];
        }
    }
}

template<int M>
__device__ __forceinline__ void reduce_z(float z[8], int lane) {
#pragma unroll
    for (int q = 0; q < 8; ++q) z[q] += xorlane<M>(z[q], lane);
}

__global__ __launch_bounds__(256) void qmlp_fused(
    const float* __restrict__ x,        // [B,8]
    const float* __restrict__ qw,       // [3,8,2]
    const float* __restrict__ W1,       // [8,64]
    const float* __restrict__ b1,       // [64]
    const float* __restrict__ W2,       // [64,256]
    const float* __restrict__ b2,       // [256]
    float* __restrict__ out,            // [B,256]
    int B)
{
    // packed per-(layer,qubit) table: {cos_ry, sin_ry, cos_rz, sin_rz} -> 1 b128 read each
    __shared__ float4 tab[NLAYERS * NQ];

    int tid = threadIdx.x;
    if (tid < NLAYERS * NQ) {
        float w0 = 0.5f * qw[tid * 2 + 0];
        float w1 = 0.5f * qw[tid * 2 + 1];
        tab[tid] = make_float4(__cosf(w0), __sinf(w0), __cosf(w1), __sinf(w1));
    }
    __syncthreads();

    int lane = tid & 63;
    int wid  = tid >> 6;
    int sample = blockIdx.x * 4 + wid;
    if (sample >= B) return;

    // ---- load x row, normalize ----
    const float4* x4 = (const float4*)(x + sample * 8);
    float4 xa = x4[0], xb = x4[1];
    float xs[8] = {xa.x, xa.y, xa.z, xa.w, xb.x, xb.y, xb.z, xb.w};
    float xmin = xs[0], xmax = xs[0];
#pragma unroll
    for (int q = 1; q < 8; ++q) {
        xmin = fminf(xmin, xs[q]);
        xmax = fmaxf(xmax, xs[q]);
    }
    float inv = 1.0f / (xmax - xmin + 1e-8f);

    // ---- encoding: construct product state directly (no gates) ----
    float cq[8], sq[8];
#pragma unroll
    for (int q = 0; q < 8; ++q) {
        float a = (xs[q] - xmin) * inv * 1.5707963267948966f; // xn * pi/2
        cq[q] = __cosf(a);
        sq[q] = __sinf(a);
    }
    float pl = 1.0f;
#pragma unroll
    for (int q = 2; q < 8; ++q) pl *= ((lane >> (q - 2)) & 1) ? sq[q] : cq[q];

    float ar[4], ai[4];
    ar[0] = pl * cq[0] * cq[1];
    ar[1] = pl * sq[0] * cq[1];
    ar[2] = pl * cq[0] * sq[1];
    ar[3] = pl * sq[0] * sq[1];
    ai[0] = 0.f; ai[1] = 0.f; ai[2] = 0.f; ai[3] = 0.f;

    // ---- variational layers ----
#pragma unroll
    for (int l = 0; l < NLAYERS; ++l) {
        const float4* tl = &tab[l * NQ];
        {
            float4 t;
            t = tl[0]; apply_ry_t<0>(t.x, t.y, ar, ai, lane); apply_rz_t<0>(t.z, t.w, ar, ai, lane);
            t = tl[1]; apply_ry_t<1>(t.x, t.y, ar, ai, lane); apply_rz_t<1>(t.z, t.w, ar, ai, lane);
            t = tl[2]; apply_ry_t<2>(t.x, t.y, ar, ai, lane); apply_rz_t<2>(t.z, t.w, ar, ai, lane);
            t = tl[3]; apply_ry_t<3>(t.x, t.y, ar, ai, lane); apply_rz_t<3>(t.z, t.w, ar, ai, lane);
            t = tl[4]; apply_ry_t<4>(t.x, t.y, ar, ai, lane); apply_rz_t<4>(t.z, t.w, ar, ai, lane);
            t = tl[5]; apply_ry_t<5>(t.x, t.y, ar, ai, lane); apply_rz_t<5>(t.z, t.w, ar, ai, lane);
            t = tl[6]; apply_ry_t<6>(t.x, t.y, ar, ai, lane); apply_rz_t<6>(t.z, t.w, ar, ai, lane);
            t = tl[7]; apply_ry_t<7>(t.x, t.y, ar, ai, lane); apply_rz_t<7>(t.z, t.w, ar, ai, lane);
        }
        apply_cnot_t<0>(ar, ai, lane);
        apply_cnot_t<1>(ar, ai, lane);
        apply_cnot_t<2>(ar, ai, lane);
        apply_cnot_t<3>(ar, ai, lane);
        apply_cnot_t<4>(ar, ai, lane);
        apply_cnot_t<5>(ar, ai, lane);
        apply_cnot_t<6>(ar, ai, lane);
        apply_cnot_t<7>(ar, ai, lane);
    }

    // ---- measurement <Z_q> ----
    float p[4];
#pragma unroll
    for (int j = 0; j < 4; ++j) p[j] = ar[j] * ar[j] + ai[j] * ai[j];

    float z[8];
    z[0] = (p[0] - p[1]) + (p[2] - p[3]);
    z[1] = (p[0] + p[1]) - (p[2] + p[3]);
    float sall = (p[0] + p[1]) + (p[2] + p[3]);
#pragma unroll
    for (int q = 2; q < 8; ++q)
        z[q] = (lane & (1 << (q - 2))) ? -sall : sall;

    reduce_z<1>(z, lane);
    reduce_z<2>(z, lane);
    reduce_z<4>(z, lane);
    reduce_z<8>(z, lane);
    reduce_z<16>(z, lane);
    reduce_z<32>(z, lane);

    // ---- MLP: h = relu(z @ W1 + b1); out = h @ W2 + b2 ----
    float h = b1[lane];
#pragma unroll
    for (int q = 0; q < 8; ++q) h += z[q] * W1[q * 64 + lane];
    h = fmaxf(h, 0.0f);

    int col = lane * 4;
    float4 acc = *(const float4*)(b2 + col);
#pragma unroll 8
    for (int i = 0; i < 64; ++i) {
        float hv = __uint_as_float(__builtin_amdgcn_readlane(__float_as_uint(h), i));
        float4 w = *(const float4*)(W2 + i * 256 + col);
        acc.x += hv * w.x;
        acc.y += hv * w.y;
        acc.z += hv * w.z;
        acc.w += hv * w.w;
    }
    *(float4*)(out + sample * 256 + col) = acc;
}

extern "C" void kernel_launch(void* const* d_in, const int* in_sizes, int n_in,
                              void* d_out, int out_size, void* d_ws, size_t ws_size,
                              hipStream_t stream) {
    const float* x  = (const float*)d_in[0];
    const float* qw = (const float*)d_in[1];
    const float* W1 = (const float*)d_in[2];
    const float* b1 = (const float*)d_in[3];
    const float* W2 = (const float*)d_in[4];
    const float* b2 = (const float*)d_in[5];
    float* out = (float*)d_out;

    int B = in_sizes[0] / NQ;          // 8192
    int blocks = (B + 3) / 4;          // 4 samples (waves) per 256-thread block

    qmlp_fused<<<blocks, 256, 0, stream>>>(x, qw, W1, b1, W2, b2, out, B);
}